// Round 3
// baseline (742.674 us; speedup 1.0000x reference)
//
#include <hip/hip_runtime.h>
#include <math.h>

#define TT 16384            // tokens
#define HD 4096             // hidden
#define NE 64               // experts
#define TM 32               // tokens per epilogue block
#define NBLK (TT / TM)      // 512 epilogue blocks
#define NTB (TT / 128)      // 128 token-blocks for gemm_v3

// ---- async global->LDS, 16B per lane (dest = wave-uniform base + lane*16) ----
__device__ __forceinline__ void async_copy16(const float* src, float* dst) {
  __builtin_amdgcn_global_load_lds(
      (const __attribute__((address_space(1))) void*)src,
      (__attribute__((address_space(3))) void*)dst, 16, 0, 0);
}

#define FMA4(A, HV, WV)                                       \
  A = fmaf((HV).x, (WV).x, A); A = fmaf((HV).y, (WV).y, A);   \
  A = fmaf((HV).z, (WV).z, A); A = fmaf((HV).w, (WV).w, A);

// =====================================================================
// gemm_v3: 128 thr = 16 token-groups (ty) x 8 expert-groups (tx, fastest).
// Thread tile 8 tok x 8 exp. X read DIRECTLY from global (8 lanes with the
// same ty issue identical addresses in one instr -> coalesced broadcast).
// Only W goes through LDS (double-buffered 2x8KB, BK=32), stored with
// phys_chunk = log_chunk ^ tx(e) so the 8 tx-lanes of a read hit 8 distinct
// bank-groups. One barrier per BK=32 (8192 FMA-cycles between barriers).
// =====================================================================
template <int KSPLIT>
__launch_bounds__(128, 3)
__global__ void gemm_v3(const float* __restrict__ X,
                        const float* __restrict__ W,
                        float* __restrict__ part) {
  constexpr int HSP = HD / KSPLIT;
  constexpr int NKT = HSP / 32;
  __shared__ __align__(16) float sW[2][NE * 32];   // 2 x 8 KB

  const int tid = threadIdx.x;
  const int tx  = tid & 7;          // expert group (8 experts)
  const int ty  = tid >> 3;         // token group (8 tokens), 0..15
  const int tb  = blockIdx.x % NTB; // token block (fast-varying: same-kz blocks co-run, share W slice in L2)
  const int kz  = blockIdx.x / NTB;
  const int t0  = tb * 128;
  const int h0  = kz * HSP;

  // ---- W staging sources (pre-swizzled logical chunk per lane) ----
  const float* srcW[4];
#pragma unroll
  for (int s = 0; s < 4; ++s) {
    const int q  = s * 128 + tid;              // 16B-chunk position in buffer
    const int e  = q >> 3;                     // expert row 0..63
    const int cl = (q & 7) ^ ((e >> 3) & 7);   // logical chunk = phys ^ tx(e)
    srcW[s] = W + (size_t)e * HD + h0 + cl * 4;
  }
  auto stage = [&](int b, int kt) {
    const int o = kt * 32;
#pragma unroll
    for (int s = 0; s < 4; ++s)
      async_copy16(srcW[s] + o, &sW[b][(s * 128 + tid) * 4]);
  };

  // ---- X row pointers (8 rows per thread; identical across the 8 tx lanes) ----
  const float* xrow[8];
#pragma unroll
  for (int i = 0; i < 8; ++i)
    xrow[i] = X + (size_t)(t0 + ty * 8 + i) * HD + h0;

  float acc[8][8];
#pragma unroll
  for (int i = 0; i < 8; ++i)
#pragma unroll
    for (int j = 0; j < 8; ++j) acc[i][j] = 0.0f;

  int buf = 0;
  stage(0, 0);
  __syncthreads();
  for (int kt = 0; kt < NKT; ++kt) {
    if (kt + 1 < NKT) stage(buf ^ 1, kt + 1);
    const int hb = kt * 32;
    const char* wbase = (const char*)(&sW[buf][0]);
#pragma unroll
    for (int p = 0; p < 8; ++p) {
      float4 xv[8], wv[8];
#pragma unroll
      for (int i = 0; i < 8; ++i)
        xv[i] = *(const float4*)(xrow[i] + hb + p * 4);
#pragma unroll
      for (int j = 0; j < 8; ++j)
        wv[j] = *(const float4*)(wbase + ((tx * 8 + j) << 7) + (((p ^ tx) & 7) << 4));
#pragma unroll
      for (int i = 0; i < 8; ++i)
#pragma unroll
        for (int j = 0; j < 8; ++j) { FMA4(acc[i][j], xv[i], wv[j]) }
    }
    __syncthreads();
    buf ^= 1;
  }

  // ---- write partial logits [kz][t][e] ----
  float* pb = part + ((size_t)kz * TT + t0 + ty * 8) * NE + tx * 8;
#pragma unroll
  for (int i = 0; i < 8; ++i) {
    *(float4*)(pb + (size_t)i * NE)     = make_float4(acc[i][0], acc[i][1], acc[i][2], acc[i][3]);
    *(float4*)(pb + (size_t)i * NE + 4) = make_float4(acc[i][4], acc[i][5], acc[i][6], acc[i][7]);
  }
}

// =====================================================================
// Epilogue: reduce KSPLIT partials -> logits, then validated softmax /
// top-2 / renorm / loss partials (identical structure to rounds 1-2).
// =====================================================================
template <int KSPLIT>
__global__ void router_epilogue(const float* __restrict__ part,
                                float* __restrict__ out,
                                float* __restrict__ pP,
                                float* __restrict__ pC,
                                float* __restrict__ pZ) {
  __shared__ float psW[4][NE];
  __shared__ float cf[NE];
  __shared__ float zb[4];

  const int tid  = threadIdx.x;
  const int blk  = blockIdx.x;
  const int tx   = tid & 15;   // expert group (4 experts each)
  const int ty   = tid >> 4;   // token group (2 tokens each), 0..15
  const int wv   = tid >> 6;   // wave id 0..3
  const int lane = tid & 63;

  if (tid < NE) cf[tid] = 0.0f;

  float lg[2][4];
#pragma unroll
  for (int i = 0; i < 2; ++i) {
    const int t = blk * TM + 2 * ty + i;
    float4 s = make_float4(0.f, 0.f, 0.f, 0.f);
#pragma unroll
    for (int k = 0; k < KSPLIT; ++k) {
      const float4 v = *(const float4*)(part + ((size_t)k * TT + t) * NE + 4 * tx);
      s.x += v.x; s.y += v.y; s.z += v.z; s.w += v.w;
    }
    lg[i][0] = s.x; lg[i][1] = s.y; lg[i][2] = s.z; lg[i][3] = s.w;
  }
  __syncthreads();   // cf init visible before atomics

  float psum[4] = {0.f, 0.f, 0.f, 0.f};
  float zc = 0.0f;
#pragma unroll
  for (int i = 0; i < 2; ++i) {
    const float l0 = lg[i][0], l1 = lg[i][1], l2 = lg[i][2], l3 = lg[i][3];
    float m = fmaxf(fmaxf(l0, l1), fmaxf(l2, l3));
    m = fmaxf(m, __shfl_xor(m, 1));
    m = fmaxf(m, __shfl_xor(m, 2));
    m = fmaxf(m, __shfl_xor(m, 4));
    m = fmaxf(m, __shfl_xor(m, 8));
    const float e0 = expf(l0 - m), e1 = expf(l1 - m);
    const float e2 = expf(l2 - m), e3 = expf(l3 - m);
    float zs = (e0 + e1) + (e2 + e3);
    zs += __shfl_xor(zs, 1);
    zs += __shfl_xor(zs, 2);
    zs += __shfl_xor(zs, 4);
    zs += __shfl_xor(zs, 8);
    const float p0 = e0 / zs, p1 = e1 / zs, p2 = e2 / zs, p3 = e3 / zs;
    psum[0] += p0; psum[1] += p1; psum[2] += p2; psum[3] += p3;

    // local top-2 among 4 experts (ascending index => ties keep lower)
    float v1 = p0, v2 = p1; int i1 = 4 * tx, i2 = 4 * tx + 1;
    if (p1 > p0) { v1 = p1; i1 = 4 * tx + 1; v2 = p0; i2 = 4 * tx; }
    if (p2 > v1) { v2 = v1; i2 = i1; v1 = p2; i1 = 4 * tx + 2; }
    else if (p2 > v2) { v2 = p2; i2 = 4 * tx + 2; }
    if (p3 > v1) { v2 = v1; i2 = i1; v1 = p3; i1 = 4 * tx + 3; }
    else if (p3 > v2) { v2 = p3; i2 = 4 * tx + 3; }

    // butterfly merge across the 16 lanes holding this token
#pragma unroll
    for (int s = 1; s <= 8; s <<= 1) {
      const float ov1 = __shfl_xor(v1, s); const int oi1 = __shfl_xor(i1, s);
      const float ov2 = __shfl_xor(v2, s); const int oi2 = __shfl_xor(i2, s);
      const bool o1 = (ov1 > v1) || (ov1 == v1 && oi1 < i1);
      if (o1) {
        const bool o2 = (ov2 > v1) || (ov2 == v1 && oi2 < i1);
        v2 = o2 ? ov2 : v1; i2 = o2 ? oi2 : i1;
        v1 = ov1; i1 = oi1;
      } else {
        const bool o2 = (ov1 > v2) || (ov1 == v2 && oi1 < i2);
        v2 = o2 ? ov1 : v2; i2 = o2 ? oi1 : i2;
      }
    }

    const float lz = m + logf(zs);
    if (tx == 0) {
      const int t = blk * TM + 2 * ty + i;
      const float den = v1 + v2 + 1e-9f;
      out[2 * t]     = v1 / den;
      out[2 * t + 1] = v2 / den;
      out[2 * TT + 2 * t]     = (float)i1;
      out[2 * TT + 2 * t + 1] = (float)i2;
      atomicAdd(&cf[i1], 1.0f);
      atomicAdd(&cf[i2], 1.0f);
      zc += lz * lz;
    }
  }

#pragma unroll
  for (int j = 0; j < 4; ++j) {
    psum[j] += __shfl_xor(psum[j], 16);
    psum[j] += __shfl_xor(psum[j], 32);
  }
  if (lane < 16) {
#pragma unroll
    for (int j = 0; j < 4; ++j) psW[wv][4 * lane + j] = psum[j];
  }
  float z = zc;
#pragma unroll
  for (int s = 1; s <= 32; s <<= 1) z += __shfl_xor(z, s);
  if (lane == 0) zb[wv] = z;
  __syncthreads();

  if (tid < NE) {
    pP[blk * NE + tid] = psW[0][tid] + psW[1][tid] + psW[2][tid] + psW[3][tid];
    pC[blk * NE + tid] = cf[tid];
  }
  if (tid == 0) pZ[blk] = zb[0] + zb[1] + zb[2] + zb[3];
}

__global__ void router_final(const float* __restrict__ pP,
                             const float* __restrict__ pC,
                             const float* __restrict__ pZ,
                             float* __restrict__ out) {
  const int e = threadIdx.x;  // 64 threads = 1 wave
  float sP = 0.f, sC = 0.f;
  for (int b = 0; b < NBLK; ++b) {
    sP += pP[b * NE + e];
    sC += pC[b * NE + e];
  }
  const float f = sC * (1.0f / (TT * 2.0f));
  const float P = sP * (1.0f / (float)TT);
  out[4 * TT + 2 + e] = f;
  float term = f * P;
#pragma unroll
  for (int s = 1; s <= 32; s <<= 1) term += __shfl_xor(term, s);
  float zs = 0.f;
  for (int b = e; b < NBLK; b += NE) zs += pZ[b];
#pragma unroll
  for (int s = 1; s <= 32; s <<= 1) zs += __shfl_xor(zs, s);
  if (e == 0) {
    out[4 * TT]     = 0.01f * ((float)NE * term);
    out[4 * TT + 1] = 0.001f * (zs / (float)TT);
  }
}

// =====================================================================
// Fallback (validated round-1 fused kernel) for tiny ws_size.
// =====================================================================
__launch_bounds__(256, 2)
__global__ void router_fused(const float* __restrict__ X,
                             const float* __restrict__ W,
                             float* __restrict__ out,
                             float* __restrict__ pP,
                             float* __restrict__ pC,
                             float* __restrict__ pZ) {
  __shared__ __align__(16) float sH[2][TM * 64];
  __shared__ __align__(16) float sW[2][NE * 64];
  __shared__ float psW[4][NE];
  __shared__ float cf[NE];
  __shared__ float zb[4];

  const int tid  = threadIdx.x;
  const int blk  = blockIdx.x;
  const int tx   = tid & 15;
  const int ty   = tid >> 4;
  const int wv   = tid >> 6;
  const int lane = tid & 63;

  if (tid < NE) cf[tid] = 0.0f;

  const int xoff = (tid & 15) << 4;
  const float* srcH[2];
  const float* srcW[4];
#pragma unroll
  for (int p = 0; p < 2; ++p) {
    const int r = ty + p * 16;
    const int sw = ((r >> 1) & 7) << 4;
    srcH[p] = X + (size_t)(blk * TM + r) * HD + ((xoff ^ sw) >> 2);
  }
#pragma unroll
  for (int p = 0; p < 4; ++p) {
    const int e = ty + p * 16;
    const int sw = ((e >> 2) & 7) << 4;
    srcW[p] = W + (size_t)e * HD + ((xoff ^ sw) >> 2);
  }

  auto stage = [&](int b, int kt) {
    const int o = kt * 64;
    float* dH = &sH[b][wv * 256];
    async_copy16(srcH[0] + o, dH);
    async_copy16(srcH[1] + o, dH + 1024);
    float* dW = &sW[b][wv * 256];
    async_copy16(srcW[0] + o, dW);
    async_copy16(srcW[1] + o, dW + 1024);
    async_copy16(srcW[2] + o, dW + 2048);
    async_copy16(srcW[3] + o, dW + 3072);
  };

  float acc[2][4] = {{0.f, 0.f, 0.f, 0.f}, {0.f, 0.f, 0.f, 0.f}};
  const int Hswz = (ty & 7) << 4;
  const int Wswz = (tx & 7) << 4;

  auto compute = [&](int b) {
    const char* hb = (const char*)(&sH[b][0]) + (ty << 9);
    const char* wb = (const char*)(&sW[b][0]) + (tx << 10);
#pragma unroll
    for (int h4 = 0; h4 < 16; ++h4) {
      const int oH = (h4 << 4) ^ Hswz;
      const int oW = (h4 << 4) ^ Wswz;
      const float4 h0 = *(const float4*)(hb + oH);
      const float4 h1 = *(const float4*)(hb + oH + 256);
      const float4 w0 = *(const float4*)(wb + oW);
      const float4 w1 = *(const float4*)(wb + oW + 256);
      const float4 w2 = *(const float4*)(wb + oW + 512);
      const float4 w3 = *(const float4*)(wb + oW + 768);
      FMA4(acc[0][0], h0, w0) FMA4(acc[0][1], h0, w1)
      FMA4(acc[0][2], h0, w2) FMA4(acc[0][3], h0, w3)
      FMA4(acc[1][0], h1, w0) FMA4(acc[1][1], h1, w1)
      FMA4(acc[1][2], h1, w2) FMA4(acc[1][3], h1, w3)
    }
  };

  int buf = 0;
  stage(0, 0);
  __syncthreads();
  for (int kt = 0; kt < 64; ++kt) {
    if (kt + 1 < 64) stage(buf ^ 1, kt + 1);
    compute(buf);
    __syncthreads();
    buf ^= 1;
  }

  float psum[4] = {0.f, 0.f, 0.f, 0.f};
  float zc = 0.0f;
#pragma unroll
  for (int i = 0; i < 2; ++i) {
    const float l0 = acc[i][0], l1 = acc[i][1], l2 = acc[i][2], l3 = acc[i][3];
    float m = fmaxf(fmaxf(l0, l1), fmaxf(l2, l3));
    m = fmaxf(m, __shfl_xor(m, 1));
    m = fmaxf(m, __shfl_xor(m, 2));
    m = fmaxf(m, __shfl_xor(m, 4));
    m = fmaxf(m, __shfl_xor(m, 8));
    const float e0 = expf(l0 - m), e1 = expf(l1 - m);
    const float e2 = expf(l2 - m), e3 = expf(l3 - m);
    float zs = (e0 + e1) + (e2 + e3);
    zs += __shfl_xor(zs, 1);
    zs += __shfl_xor(zs, 2);
    zs += __shfl_xor(zs, 4);
    zs += __shfl_xor(zs, 8);
    const float p0 = e0 / zs, p1 = e1 / zs, p2 = e2 / zs, p3 = e3 / zs;
    psum[0] += p0; psum[1] += p1; psum[2] += p2; psum[3] += p3;

    float v1 = p0, v2 = p1; int i1 = 4 * tx, i2 = 4 * tx + 1;
    if (p1 > p0) { v1 = p1; i1 = 4 * tx + 1; v2 = p0; i2 = 4 * tx; }
    if (p2 > v1) { v2 = v1; i2 = i1; v1 = p2; i1 = 4 * tx + 2; }
    else if (p2 > v2) { v2 = p2; i2 = 4 * tx + 2; }
    if (p3 > v1) { v2 = v1; i2 = i1; v1 = p3; i1 = 4 * tx + 3; }
    else if (p3 > v2) { v2 = p3; i2 = 4 * tx + 3; }

#pragma unroll
    for (int s = 1; s <= 8; s <<= 1) {
      const float ov1 = __shfl_xor(v1, s); const int oi1 = __shfl_xor(i1, s);
      const float ov2 = __shfl_xor(v2, s); const int oi2 = __shfl_xor(i2, s);
      const bool o1 = (ov1 > v1) || (ov1 == v1 && oi1 < i1);
      if (o1) {
        const bool o2 = (ov2 > v1) || (ov2 == v1 && oi2 < i1);
        v2 = o2 ? ov2 : v1; i2 = o2 ? oi2 : i1;
        v1 = ov1; i1 = oi1;
      } else {
        const bool o2 = (ov1 > v2) || (ov1 == v2 && oi1 < i2);
        v2 = o2 ? ov1 : v2; i2 = o2 ? oi1 : i2;
      }
    }

    const float lz = m + logf(zs);
    if (tx == 0) {
      const int t = blk * TM + 2 * ty + i;
      const float den = v1 + v2 + 1e-9f;
      out[2 * t]     = v1 / den;
      out[2 * t + 1] = v2 / den;
      out[2 * TT + 2 * t]     = (float)i1;
      out[2 * TT + 2 * t + 1] = (float)i2;
      atomicAdd(&cf[i1], 1.0f);
      atomicAdd(&cf[i2], 1.0f);
      zc += lz * lz;
    }
  }

#pragma unroll
  for (int j = 0; j < 4; ++j) {
    psum[j] += __shfl_xor(psum[j], 16);
    psum[j] += __shfl_xor(psum[j], 32);
  }
  if (lane < 16) {
#pragma unroll
    for (int j = 0; j < 4; ++j) psW[wv][4 * lane + j] = psum[j];
  }
  float z = zc;
#pragma unroll
  for (int s = 1; s <= 32; s <<= 1) z += __shfl_xor(z, s);
  if (lane == 0) zb[wv] = z;
  __syncthreads();

  if (tid < NE) {
    pP[blk * NE + tid] = psW[0][tid] + psW[1][tid] + psW[2][tid] + psW[3][tid];
    pC[blk * NE + tid] = cf[tid];
  }
  if (tid == 0) pZ[blk] = zb[0] + zb[1] + zb[2] + zb[3];
}

extern "C" void kernel_launch(void* const* d_in, const int* in_sizes, int n_in,
                              void* d_out, int out_size, void* d_ws, size_t ws_size,
                              hipStream_t stream) {
  const float* X = (const float*)d_in[0];   // [16384, 4096] f32
  const float* W = (const float*)d_in[1];   // [64, 4096] f32
  float* out = (float*)d_out;
  (void)in_sizes; (void)n_in; (void)out_size;

  const size_t AUXF = (size_t)NBLK * NE * 2 + NBLK;
  const size_t P16  = 16UL * TT * NE;
  const size_t P8   = 8UL * TT * NE;

  if (ws_size >= (P16 + AUXF) * sizeof(float)) {
    float* part = (float*)d_ws;
    float* pP = part + P16;
    float* pC = pP + NBLK * NE;
    float* pZ = pC + NBLK * NE;
    gemm_v3<16><<<dim3(NTB * 16), dim3(128), 0, stream>>>(X, W, part);
    router_epilogue<16><<<dim3(NBLK), dim3(256), 0, stream>>>(part, out, pP, pC, pZ);
    router_final<<<dim3(1), dim3(NE), 0, stream>>>(pP, pC, pZ, out);
  } else if (ws_size >= (P8 + AUXF) * sizeof(float)) {
    float* part = (float*)d_ws;
    float* pP = part + P8;
    float* pC = pP + NBLK * NE;
    float* pZ = pC + NBLK * NE;
    gemm_v3<8><<<dim3(NTB * 8), dim3(128), 0, stream>>>(X, W, part);
    router_epilogue<8><<<dim3(NBLK), dim3(256), 0, stream>>>(part, out, pP, pC, pZ);
    router_final<<<dim3(1), dim3(NE), 0, stream>>>(pP, pC, pZ, out);
  } else {
    float* pP = (float*)d_ws;
    float* pC = pP + NBLK * NE;
    float* pZ = pC + NBLK * NE;
    router_fused<<<dim3(NBLK), dim3(256), 0, stream>>>(X, W, out, pP, pC, pZ);
    router_final<<<dim3(1), dim3(NE), 0, stream>>>(pP, pC, pZ, out);
  }
}

// Round 4
// 570.183 us; speedup vs baseline: 1.3025x; 1.3025x over previous
//
#include <hip/hip_runtime.h>
#include <math.h>

#define TT 16384            // tokens
#define HD 4096             // hidden
#define NE 64               // experts
#define TM 32               // tokens per epilogue block
#define NBLK (TT / TM)      // 512 epilogue blocks
// ---- v4 geometry: lane = token ----
#define KS8 8               // split-K over h
#define HSP (HD / KS8)      // 512 h per split
#define TKB 256             // tokens per block (= threads)
#define NTB4 (TT / TKB)     // 64 token-blocks (x8 kz = 512 blocks)
#define BK 32               // h per staged tile
#define NKT (HSP / BK)      // 16 k-iterations

// ---- async global->LDS: LDS dest is wave-uniform base; HW adds lane*16 ----
__device__ __forceinline__ void async_copy16(const float* src, float* dst) {
  __builtin_amdgcn_global_load_lds(
      (const __attribute__((address_space(1))) void*)src,
      (__attribute__((address_space(3))) void*)dst, 16, 0, 0);
}

#define FMA4(A, HV, WV)                                       \
  A = fmaf((HV).x, (WV).x, A); A = fmaf((HV).y, (WV).y, A);   \
  A = fmaf((HV).z, (WV).z, A); A = fmaf((HV).w, (WV).w, A);

// =====================================================================
// gemm_v4: 256 threads = 256 tokens; acc[64] = full expert row per lane.
// X staged to LDS (coalesced full-128B-line staging, XOR-swizzled chunks:
// phys chunk p of token row t holds logical chunk p ^ (t&7)); each X value
// read once from LDS, reused 64x in registers. W loads are wave-uniform
// (TA dedup -> L1 hit / scalar path); no LDS for W.
// =====================================================================
__launch_bounds__(256, 2)
__global__ void gemm_v4(const float* __restrict__ X,
                        const float* __restrict__ W,
                        float* __restrict__ part) {
  __shared__ __align__(16) float sX[2][TKB * BK];   // 2 x 32 KB

  const int tid  = threadIdx.x;
  const int lane = tid & 63;
  const int w    = tid >> 6;        // wave 0..3
  const int tb   = blockIdx.x >> 3;
  const int kz   = blockIdx.x & 7;
  const int t0   = tb * TKB;
  const int h0   = kz * HSP;

  // ---- staging: instr (w,i) covers rows w*64 + i*8 + (lane>>3), full 128B.
  // lane supplies logical chunk c = (lane&7) ^ ((lane>>3)&7); the HW writes
  // it at phys slot lane -> phys p holds logical p ^ (t&7).  [round-2 proven]
  const int lr = lane >> 3;
  const int c  = (lane & 7) ^ (lr & 7);
  const float* src = X + (size_t)(t0 + w * 64 + lr) * HD + h0 + c * 4;

  auto stage = [&](int b, int kt) {
#pragma unroll
    for (int i = 0; i < 8; ++i)
      async_copy16(src + (size_t)i * 8 * HD + kt * BK,
                   &sX[b][(w * 512 + i * 64) * 4]);   // wave-uniform dest
  };

  const int t     = tid;        // this lane's token (0..255)
  const int myswz = tid & 7;

  float acc[64];
#pragma unroll
  for (int e = 0; e < 64; ++e) acc[e] = 0.0f;

  const float* Wp = W + h0;

  int buf = 0;
  stage(0, 0);
  __syncthreads();
  for (int kt = 0; kt < NKT; ++kt) {
    if (kt + 1 < NKT) stage(buf ^ 1, kt + 1);

    // X row for this token: 8 x b128, de-swizzled (conflict-free groups)
    float4 xv[8];
#pragma unroll
    for (int k = 0; k < 8; ++k)
      xv[k] = *(const float4*)(&sX[buf][t * BK + ((k ^ myswz) << 2)]);

    // experts: 16 groups of 4; W loads wave-uniform
#pragma unroll
    for (int e4 = 0; e4 < 16; ++e4) {
      const float* wb = Wp + (size_t)(e4 * 4) * HD + kt * BK;
#pragma unroll
      for (int k = 0; k < 8; ++k) {
        const float4 w0 = *(const float4*)(wb + 0 * HD + k * 4);
        const float4 w1 = *(const float4*)(wb + 1 * HD + k * 4);
        const float4 w2 = *(const float4*)(wb + 2 * HD + k * 4);
        const float4 w3 = *(const float4*)(wb + 3 * HD + k * 4);
        FMA4(acc[e4 * 4 + 0], xv[k], w0)
        FMA4(acc[e4 * 4 + 1], xv[k], w1)
        FMA4(acc[e4 * 4 + 2], xv[k], w2)
        FMA4(acc[e4 * 4 + 3], xv[k], w3)
      }
    }
    __syncthreads();
    buf ^= 1;
  }

  // ---- write partial logits [kz][t][e]: 256B contiguous per lane ----
  float* pb = part + ((size_t)kz * TT + t0 + t) * NE;
#pragma unroll
  for (int q = 0; q < 16; ++q)
    *(float4*)(pb + q * 4) = make_float4(acc[4 * q], acc[4 * q + 1],
                                         acc[4 * q + 2], acc[4 * q + 3]);
}

// =====================================================================
// Epilogue: reduce KS8 partials -> logits, then validated softmax /
// top-2 / renorm / loss partials (identical to rounds 1-3, absmax 0.0).
// =====================================================================
__global__ void router_epilogue(const float* __restrict__ part,
                                float* __restrict__ out,
                                float* __restrict__ pP,
                                float* __restrict__ pC,
                                float* __restrict__ pZ) {
  __shared__ float psW[4][NE];
  __shared__ float cf[NE];
  __shared__ float zb[4];

  const int tid  = threadIdx.x;
  const int blk  = blockIdx.x;
  const int tx   = tid & 15;   // expert group (4 experts each)
  const int ty   = tid >> 4;   // token group (2 tokens each), 0..15
  const int wv   = tid >> 6;   // wave id 0..3
  const int lane = tid & 63;

  if (tid < NE) cf[tid] = 0.0f;

  float lg[2][4];
#pragma unroll
  for (int i = 0; i < 2; ++i) {
    const int t = blk * TM + 2 * ty + i;
    float4 s = make_float4(0.f, 0.f, 0.f, 0.f);
#pragma unroll
    for (int k = 0; k < KS8; ++k) {
      const float4 v = *(const float4*)(part + ((size_t)k * TT + t) * NE + 4 * tx);
      s.x += v.x; s.y += v.y; s.z += v.z; s.w += v.w;
    }
    lg[i][0] = s.x; lg[i][1] = s.y; lg[i][2] = s.z; lg[i][3] = s.w;
  }
  __syncthreads();   // cf init visible before atomics

  float psum[4] = {0.f, 0.f, 0.f, 0.f};
  float zc = 0.0f;
#pragma unroll
  for (int i = 0; i < 2; ++i) {
    const float l0 = lg[i][0], l1 = lg[i][1], l2 = lg[i][2], l3 = lg[i][3];
    float m = fmaxf(fmaxf(l0, l1), fmaxf(l2, l3));
    m = fmaxf(m, __shfl_xor(m, 1));
    m = fmaxf(m, __shfl_xor(m, 2));
    m = fmaxf(m, __shfl_xor(m, 4));
    m = fmaxf(m, __shfl_xor(m, 8));
    const float e0 = expf(l0 - m), e1 = expf(l1 - m);
    const float e2 = expf(l2 - m), e3 = expf(l3 - m);
    float zs = (e0 + e1) + (e2 + e3);
    zs += __shfl_xor(zs, 1);
    zs += __shfl_xor(zs, 2);
    zs += __shfl_xor(zs, 4);
    zs += __shfl_xor(zs, 8);
    const float p0 = e0 / zs, p1 = e1 / zs, p2 = e2 / zs, p3 = e3 / zs;
    psum[0] += p0; psum[1] += p1; psum[2] += p2; psum[3] += p3;

    // local top-2 among 4 experts (ascending index => ties keep lower)
    float v1 = p0, v2 = p1; int i1 = 4 * tx, i2 = 4 * tx + 1;
    if (p1 > p0) { v1 = p1; i1 = 4 * tx + 1; v2 = p0; i2 = 4 * tx; }
    if (p2 > v1) { v2 = v1; i2 = i1; v1 = p2; i1 = 4 * tx + 2; }
    else if (p2 > v2) { v2 = p2; i2 = 4 * tx + 2; }
    if (p3 > v1) { v2 = v1; i2 = i1; v1 = p3; i1 = 4 * tx + 3; }
    else if (p3 > v2) { v2 = p3; i2 = 4 * tx + 3; }

    // butterfly merge across the 16 lanes holding this token
#pragma unroll
    for (int s = 1; s <= 8; s <<= 1) {
      const float ov1 = __shfl_xor(v1, s); const int oi1 = __shfl_xor(i1, s);
      const float ov2 = __shfl_xor(v2, s); const int oi2 = __shfl_xor(i2, s);
      const bool o1 = (ov1 > v1) || (ov1 == v1 && oi1 < i1);
      if (o1) {
        const bool o2 = (ov2 > v1) || (ov2 == v1 && oi2 < i1);
        v2 = o2 ? ov2 : v1; i2 = o2 ? oi2 : i1;
        v1 = ov1; i1 = oi1;
      } else {
        const bool o2 = (ov1 > v2) || (ov1 == v2 && oi1 < i2);
        v2 = o2 ? ov1 : v2; i2 = o2 ? oi1 : i2;
      }
    }

    const float lz = m + logf(zs);
    if (tx == 0) {
      const int t = blk * TM + 2 * ty + i;
      const float den = v1 + v2 + 1e-9f;
      out[2 * t]     = v1 / den;
      out[2 * t + 1] = v2 / den;
      out[2 * TT + 2 * t]     = (float)i1;
      out[2 * TT + 2 * t + 1] = (float)i2;
      atomicAdd(&cf[i1], 1.0f);
      atomicAdd(&cf[i2], 1.0f);
      zc += lz * lz;
    }
  }

#pragma unroll
  for (int j = 0; j < 4; ++j) {
    psum[j] += __shfl_xor(psum[j], 16);
    psum[j] += __shfl_xor(psum[j], 32);
  }
  if (lane < 16) {
#pragma unroll
    for (int j = 0; j < 4; ++j) psW[wv][4 * lane + j] = psum[j];
  }
  float z = zc;
#pragma unroll
  for (int s = 1; s <= 32; s <<= 1) z += __shfl_xor(z, s);
  if (lane == 0) zb[wv] = z;
  __syncthreads();

  if (tid < NE) {
    pP[blk * NE + tid] = psW[0][tid] + psW[1][tid] + psW[2][tid] + psW[3][tid];
    pC[blk * NE + tid] = cf[tid];
  }
  if (tid == 0) pZ[blk] = zb[0] + zb[1] + zb[2] + zb[3];
}

__global__ void router_final(const float* __restrict__ pP,
                             const float* __restrict__ pC,
                             const float* __restrict__ pZ,
                             float* __restrict__ out) {
  const int e = threadIdx.x;  // 64 threads = 1 wave
  float sP = 0.f, sC = 0.f;
  for (int b = 0; b < NBLK; ++b) {
    sP += pP[b * NE + e];
    sC += pC[b * NE + e];
  }
  const float f = sC * (1.0f / (TT * 2.0f));
  const float P = sP * (1.0f / (float)TT);
  out[4 * TT + 2 + e] = f;
  float term = f * P;
#pragma unroll
  for (int s = 1; s <= 32; s <<= 1) term += __shfl_xor(term, s);
  float zs = 0.f;
  for (int b = e; b < NBLK; b += NE) zs += pZ[b];
#pragma unroll
  for (int s = 1; s <= 32; s <<= 1) zs += __shfl_xor(zs, s);
  if (e == 0) {
    out[4 * TT]     = 0.01f * ((float)NE * term);
    out[4 * TT + 1] = 0.001f * (zs / (float)TT);
  }
}

// =====================================================================
// Fallback (validated round-1 fused kernel) for tiny ws_size.
// =====================================================================
__launch_bounds__(256, 2)
__global__ void router_fused(const float* __restrict__ X,
                             const float* __restrict__ W,
                             float* __restrict__ out,
                             float* __restrict__ pP,
                             float* __restrict__ pC,
                             float* __restrict__ pZ) {
  __shared__ __align__(16) float sH[2][TM * 64];
  __shared__ __align__(16) float sW[2][NE * 64];
  __shared__ float psW[4][NE];
  __shared__ float cf[NE];
  __shared__ float zb[4];

  const int tid  = threadIdx.x;
  const int blk  = blockIdx.x;
  const int tx   = tid & 15;
  const int ty   = tid >> 4;
  const int wv   = tid >> 6;
  const int lane = tid & 63;

  if (tid < NE) cf[tid] = 0.0f;

  const int xoff = (tid & 15) << 4;
  const float* srcH[2];
  const float* srcW[4];
#pragma unroll
  for (int p = 0; p < 2; ++p) {
    const int r = ty + p * 16;
    const int sw = ((r >> 1) & 7) << 4;
    srcH[p] = X + (size_t)(blk * TM + r) * HD + ((xoff ^ sw) >> 2);
  }
#pragma unroll
  for (int p = 0; p < 4; ++p) {
    const int e = ty + p * 16;
    const int sw = ((e >> 2) & 7) << 4;
    srcW[p] = W + (size_t)e * HD + ((xoff ^ sw) >> 2);
  }

  auto stage = [&](int b, int kt) {
    const int o = kt * 64;
    float* dH = &sH[b][wv * 256];
    async_copy16(srcH[0] + o, dH);
    async_copy16(srcH[1] + o, dH + 1024);
    float* dW = &sW[b][wv * 256];
    async_copy16(srcW[0] + o, dW);
    async_copy16(srcW[1] + o, dW + 1024);
    async_copy16(srcW[2] + o, dW + 2048);
    async_copy16(srcW[3] + o, dW + 3072);
  };

  float acc[2][4] = {{0.f, 0.f, 0.f, 0.f}, {0.f, 0.f, 0.f, 0.f}};
  const int Hswz = (ty & 7) << 4;
  const int Wswz = (tx & 7) << 4;

  auto compute = [&](int b) {
    const char* hb = (const char*)(&sH[b][0]) + (ty << 9);
    const char* wb = (const char*)(&sW[b][0]) + (tx << 10);
#pragma unroll
    for (int h4 = 0; h4 < 16; ++h4) {
      const int oH = (h4 << 4) ^ Hswz;
      const int oW = (h4 << 4) ^ Wswz;
      const float4 h0 = *(const float4*)(hb + oH);
      const float4 h1 = *(const float4*)(hb + oH + 256);
      const float4 w0 = *(const float4*)(wb + oW);
      const float4 w1 = *(const float4*)(wb + oW + 256);
      const float4 w2 = *(const float4*)(wb + oW + 512);
      const float4 w3 = *(const float4*)(wb + oW + 768);
      FMA4(acc[0][0], h0, w0) FMA4(acc[0][1], h0, w1)
      FMA4(acc[0][2], h0, w2) FMA4(acc[0][3], h0, w3)
      FMA4(acc[1][0], h1, w0) FMA4(acc[1][1], h1, w1)
      FMA4(acc[1][2], h1, w2) FMA4(acc[1][3], h1, w3)
    }
  };

  int buf = 0;
  stage(0, 0);
  __syncthreads();
  for (int kt = 0; kt < 64; ++kt) {
    if (kt + 1 < 64) stage(buf ^ 1, kt + 1);
    compute(buf);
    __syncthreads();
    buf ^= 1;
  }

  float psum[4] = {0.f, 0.f, 0.f, 0.f};
  float zc = 0.0f;
#pragma unroll
  for (int i = 0; i < 2; ++i) {
    const float l0 = acc[i][0], l1 = acc[i][1], l2 = acc[i][2], l3 = acc[i][3];
    float m = fmaxf(fmaxf(l0, l1), fmaxf(l2, l3));
    m = fmaxf(m, __shfl_xor(m, 1));
    m = fmaxf(m, __shfl_xor(m, 2));
    m = fmaxf(m, __shfl_xor(m, 4));
    m = fmaxf(m, __shfl_xor(m, 8));
    const float e0 = expf(l0 - m), e1 = expf(l1 - m);
    const float e2 = expf(l2 - m), e3 = expf(l3 - m);
    float zs = (e0 + e1) + (e2 + e3);
    zs += __shfl_xor(zs, 1);
    zs += __shfl_xor(zs, 2);
    zs += __shfl_xor(zs, 4);
    zs += __shfl_xor(zs, 8);
    const float p0 = e0 / zs, p1 = e1 / zs, p2 = e2 / zs, p3 = e3 / zs;
    psum[0] += p0; psum[1] += p1; psum[2] += p2; psum[3] += p3;

    float v1 = p0, v2 = p1; int i1 = 4 * tx, i2 = 4 * tx + 1;
    if (p1 > p0) { v1 = p1; i1 = 4 * tx + 1; v2 = p0; i2 = 4 * tx; }
    if (p2 > v1) { v2 = v1; i2 = i1; v1 = p2; i1 = 4 * tx + 2; }
    else if (p2 > v2) { v2 = p2; i2 = 4 * tx + 2; }
    if (p3 > v1) { v2 = v1; i2 = i1; v1 = p3; i1 = 4 * tx + 3; }
    else if (p3 > v2) { v2 = p3; i2 = 4 * tx + 3; }

#pragma unroll
    for (int s = 1; s <= 8; s <<= 1) {
      const float ov1 = __shfl_xor(v1, s); const int oi1 = __shfl_xor(i1, s);
      const float ov2 = __shfl_xor(v2, s); const int oi2 = __shfl_xor(i2, s);
      const bool o1 = (ov1 > v1) || (ov1 == v1 && oi1 < i1);
      if (o1) {
        const bool o2 = (ov2 > v1) || (ov2 == v1 && oi2 < i1);
        v2 = o2 ? ov2 : v1; i2 = o2 ? oi2 : i1;
        v1 = ov1; i1 = oi1;
      } else {
        const bool o2 = (ov1 > v2) || (ov1 == v2 && oi1 < i2);
        v2 = o2 ? ov1 : v2; i2 = o2 ? oi1 : i2;
      }
    }

    const float lz = m + logf(zs);
    if (tx == 0) {
      const int t = blk * TM + 2 * ty + i;
      const float den = v1 + v2 + 1e-9f;
      out[2 * t]     = v1 / den;
      out[2 * t + 1] = v2 / den;
      out[2 * TT + 2 * t]     = (float)i1;
      out[2 * TT + 2 * t + 1] = (float)i2;
      atomicAdd(&cf[i1], 1.0f);
      atomicAdd(&cf[i2], 1.0f);
      zc += lz * lz;
    }
  }

#pragma unroll
  for (int j = 0; j < 4; ++j) {
    psum[j] += __shfl_xor(psum[j], 16);
    psum[j] += __shfl_xor(psum[j], 32);
  }
  if (lane < 16) {
#pragma unroll
    for (int j = 0; j < 4; ++j) psW[wv][4 * lane + j] = psum[j];
  }
  float z = zc;
#pragma unroll
  for (int s = 1; s <= 32; s <<= 1) z += __shfl_xor(z, s);
  if (lane == 0) zb[wv] = z;
  __syncthreads();

  if (tid < NE) {
    pP[blk * NE + tid] = psW[0][tid] + psW[1][tid] + psW[2][tid] + psW[3][tid];
    pC[blk * NE + tid] = cf[tid];
  }
  if (tid == 0) pZ[blk] = zb[0] + zb[1] + zb[2] + zb[3];
}

extern "C" void kernel_launch(void* const* d_in, const int* in_sizes, int n_in,
                              void* d_out, int out_size, void* d_ws, size_t ws_size,
                              hipStream_t stream) {
  const float* X = (const float*)d_in[0];   // [16384, 4096] f32
  const float* W = (const float*)d_in[1];   // [64, 4096] f32
  float* out = (float*)d_out;
  (void)in_sizes; (void)n_in; (void)out_size;

  const size_t AUXF = (size_t)NBLK * NE * 2 + NBLK;
  const size_t P8   = (size_t)KS8 * TT * NE;

  if (ws_size >= (P8 + AUXF) * sizeof(float)) {
    float* part = (float*)d_ws;
    float* pP = part + P8;
    float* pC = pP + NBLK * NE;
    float* pZ = pC + NBLK * NE;
    gemm_v4<<<dim3(NTB4 * KS8), dim3(256), 0, stream>>>(X, W, part);
    router_epilogue<<<dim3(NBLK), dim3(256), 0, stream>>>(part, out, pP, pC, pZ);
    router_final<<<dim3(1), dim3(NE), 0, stream>>>(pP, pC, pZ, out);
  } else {
    float* pP = (float*)d_ws;
    float* pC = pP + NBLK * NE;
    float* pZ = pC + NBLK * NE;
    router_fused<<<dim3(NBLK), dim3(256), 0, stream>>>(X, W, out, pP, pC, pZ);
    router_final<<<dim3(1), dim3(NE), 0, stream>>>(pP, pC, pZ, out);
  }
}

// Round 5
// 508.686 us; speedup vs baseline: 1.4600x; 1.1209x over previous
//
#include <hip/hip_runtime.h>
#include <math.h>

#define TT 16384            // tokens
#define HD 4096             // hidden
#define NE 64               // experts
#define TM 32               // tokens per epilogue block
#define NBLK (TT / TM)      // 512 epilogue blocks
// ---- MFMA gemm geometry ----
#define TB5 32              // tokens per block
#define NB5 (TT / TB5)      // 512 blocks (2 per CU)
#define BK5 64              // h per staged tile
#define NKT5 (HD / BK5)     // 64 k-iterations
#define TAU 1e-5f           // near-tie fixup threshold (prob units)

typedef __attribute__((ext_vector_type(8))) short s8v;   // 8 x bf16
typedef __attribute__((ext_vector_type(4))) float f4v;   // MFMA acc

// ---- async global->LDS: dest wave-uniform base; HW adds lane*16 ----
__device__ __forceinline__ void async16(const void* src, void* dst) {
  __builtin_amdgcn_global_load_lds(
      (const __attribute__((address_space(1))) void*)src,
      (__attribute__((address_space(3))) void*)dst, 16, 0, 0);
}

#define FMA4(A, HV, WV)                                       \
  A = fmaf((HV).x, (WV).x, A); A = fmaf((HV).y, (WV).y, A);   \
  A = fmaf((HV).z, (WV).z, A); A = fmaf((HV).w, (WV).w, A);

// RNE float->bf16 (bit trick; inputs are normal randoms, no NaN)
__device__ __forceinline__ unsigned short f2bf(float f) {
  unsigned int u = __float_as_uint(f);
  return (unsigned short)((u + 0x7FFFu + ((u >> 16) & 1u)) >> 16);
}
__device__ __forceinline__ float bf2f(unsigned short h) {
  return __uint_as_float(((unsigned int)h) << 16);
}

__device__ __forceinline__ void split8(float4 a, float4 b, s8v& hi, s8v& lo) {
  float v[8] = {a.x, a.y, a.z, a.w, b.x, b.y, b.z, b.w};
#pragma unroll
  for (int i = 0; i < 8; ++i) {
    unsigned short h = f2bf(v[i]);
    unsigned short l = f2bf(v[i] - bf2f(h));
    hi[i] = (short)h; lo[i] = (short)l;
  }
}

// =====================================================================
// Kernel 0: W fp32 -> bf16 hi/lo planes in workspace.
// =====================================================================
__global__ void wconv(const float* __restrict__ W,
                      unsigned short* __restrict__ WH,
                      unsigned short* __restrict__ WL) {
  const int i = blockIdx.x * 256 + threadIdx.x;   // 65536 float4 groups
  const float4 v = *(const float4*)(W + (size_t)i * 4);
  float x[4] = {v.x, v.y, v.z, v.w};
#pragma unroll
  for (int j = 0; j < 4; ++j) {
    unsigned short h = f2bf(x[j]);
    WH[(size_t)i * 4 + j] = h;
    WL[(size_t)i * 4 + j] = f2bf(x[j] - bf2f(h));
  }
}

// =====================================================================
// Kernel 1: bf16x3 MFMA GEMM, logits -> part[t][e] fp32.
// 256 thr = 4 waves. Wave w: m-frag (w>>1) of 2 (16 tokens), experts
// (w&1)*32..+31 (2 n-frags). 3 MFMA per (frag, K-step): xh*wh+xh*wl+xl*wh.
// X staged fp32 via global_load_lds, converted in-reg; W staged as bf16
// hi/lo planes. XOR chunk swizzles keyed on row&7 (distinct per 8-lane
// phase -> conflict-free b128 reads).
// =====================================================================
__launch_bounds__(256, 2)
__global__ void gemm_mfma(const float* __restrict__ X,
                          const unsigned short* __restrict__ WH,
                          const unsigned short* __restrict__ WL,
                          float* __restrict__ part) {
  __shared__ __align__(16) float          sX[2][TB5 * BK5];  // 2 x 8 KB
  __shared__ __align__(16) unsigned short sH[2][NE * BK5];   // 2 x 8 KB
  __shared__ __align__(16) unsigned short sL[2][NE * BK5];   // 2 x 8 KB

  const int tid  = threadIdx.x;
  const int lane = tid & 63;
  const int w    = tid >> 6;
  const int t0   = blockIdx.x * TB5;

  // ---- staging sources (pre-swizzled per-lane global addresses) ----
  // X: instr (w,ih) covers 4 token rows (w*8+ih*4+(lane>>4)), 16 chunks/row.
  const float* srcX[2];
#pragma unroll
  for (int ih = 0; ih < 2; ++ih) {
    const int row = w * 8 + ih * 4 + (lane >> 4);
    const int key = (ih * 4 + (lane >> 4)) & 7;          // row & 7
    const int c   = (lane & 15) ^ key;
    srcX[ih] = X + (size_t)(t0 + row) * HD + c * 4;
  }
  // W: instr (w,ih) covers 8 expert rows (w*16+ih*8+(lane>>3)), 8 chunks/row.
  const unsigned short* srcH[2];
  const unsigned short* srcL[2];
#pragma unroll
  for (int ih = 0; ih < 2; ++ih) {
    const int e = w * 16 + ih * 8 + (lane >> 3);
    const int c = (lane & 7) ^ (lane >> 3);              // key = e & 7
    srcH[ih] = WH + (size_t)e * HD + c * 8;
    srcL[ih] = WL + (size_t)e * HD + c * 8;
  }

  auto stage = [&](int b, int kt) {
    const int o = kt * BK5;
#pragma unroll
    for (int ih = 0; ih < 2; ++ih)
      async16(srcX[ih] + o, &sX[b][(w * 8 + ih * 4) * BK5]);
#pragma unroll
    for (int ih = 0; ih < 2; ++ih)
      async16(srcH[ih] + o, &sH[b][(w * 16 + ih * 8) * BK5]);
#pragma unroll
    for (int ih = 0; ih < 2; ++ih)
      async16(srcL[ih] + o, &sL[b][(w * 16 + ih * 8) * BK5]);
  };

  const int fr    = lane & 15;
  const int fq    = lane >> 4;
  const int tloc  = (w >> 1) * 16 + fr;   // A-frag token row in block
  const int keyA  = fr & 7;               // tloc & 7
  const int ebase = (w & 1) * 32;

  f4v acc[2];
  acc[0] = (f4v)(0.0f); acc[1] = (f4v)(0.0f);

  int buf = 0;
  stage(0, 0);
  __syncthreads();
  for (int kt = 0; kt < NKT5; ++kt) {
    if (kt + 1 < NKT5) stage(buf ^ 1, kt + 1);
#pragma unroll
    for (int ks = 0; ks < 2; ++ks) {
      // A-frag: 8 f32 at k = fq*8 + ks*32, row tloc (swizzled chunks)
      const int c0 = fq * 2 + ks * 8;
      const float4 xa = *(const float4*)(&sX[buf][tloc * BK5 + (((c0)     ^ keyA) << 2)]);
      const float4 xb = *(const float4*)(&sX[buf][tloc * BK5 + (((c0 + 1) ^ keyA) << 2)]);
      s8v ah, al;
      split8(xa, xb, ah, al);
#pragma unroll
      for (int nf = 0; nf < 2; ++nf) {
        const int eg = ebase + nf * 16 + fr;
        const int c  = (fq + ks * 4) ^ (eg & 7);
        const s8v bh = *(const s8v*)(&sH[buf][eg * BK5 + c * 8]);
        const s8v bl = *(const s8v*)(&sL[buf][eg * BK5 + c * 8]);
        acc[nf] = __builtin_amdgcn_mfma_f32_16x16x32_bf16(ah, bh, acc[nf], 0, 0, 0);
        acc[nf] = __builtin_amdgcn_mfma_f32_16x16x32_bf16(ah, bl, acc[nf], 0, 0, 0);
        acc[nf] = __builtin_amdgcn_mfma_f32_16x16x32_bf16(al, bh, acc[nf], 0, 0, 0);
      }
    }
    __syncthreads();
    buf ^= 1;
  }

  // D: col = lane&15 (expert), row = fq*4 + i (token)
#pragma unroll
  for (int nf = 0; nf < 2; ++nf) {
    const int e = ebase + nf * 16 + fr;
#pragma unroll
    for (int i = 0; i < 4; ++i) {
      const int t = t0 + (w >> 1) * 16 + fq * 4 + i;
      part[(size_t)t * NE + e] = acc[nf][i];
    }
  }
}

// =====================================================================
// Kernel 2: epilogue. Approx logits -> softmax/top-2; near-tie tokens
// (prob-gap < TAU) get exact fp32 recompute (R1-validated ascending-FMA
// order). Loss partials as in validated rounds 1-4.
// =====================================================================
__global__ void router_epilogue(const float* __restrict__ part,
                                const float* __restrict__ Xg,
                                const float* __restrict__ Wg,
                                float* __restrict__ out,
                                float* __restrict__ pP,
                                float* __restrict__ pC,
                                float* __restrict__ pZ) {
  __shared__ float psW[4][NE];
  __shared__ float cf[NE];
  __shared__ float zb[4];

  const int tid  = threadIdx.x;
  const int blk  = blockIdx.x;
  const int tx   = tid & 15;   // expert group (4 experts each)
  const int ty   = tid >> 4;   // token group (2 tokens each)
  const int wv   = tid >> 6;
  const int lane = tid & 63;

  if (tid < NE) cf[tid] = 0.0f;
  __syncthreads();

  float psum[4] = {0.f, 0.f, 0.f, 0.f};
  float zc = 0.0f;
#pragma unroll
  for (int i = 0; i < 2; ++i) {
    const int t = blk * TM + 2 * ty + i;
    const float4 lv = *(const float4*)(part + (size_t)t * NE + 4 * tx);
    float l0 = lv.x, l1 = lv.y, l2 = lv.z, l3 = lv.w;

    float m, zs, p0, p1, p2, p3, v1, v2;
    int i1, i2;
    for (int attempt = 0; attempt < 2; ++attempt) {
      m = fmaxf(fmaxf(l0, l1), fmaxf(l2, l3));
      m = fmaxf(m, __shfl_xor(m, 1));
      m = fmaxf(m, __shfl_xor(m, 2));
      m = fmaxf(m, __shfl_xor(m, 4));
      m = fmaxf(m, __shfl_xor(m, 8));
      const float e0 = expf(l0 - m), e1 = expf(l1 - m);
      const float e2 = expf(l2 - m), e3 = expf(l3 - m);
      zs = (e0 + e1) + (e2 + e3);
      zs += __shfl_xor(zs, 1);
      zs += __shfl_xor(zs, 2);
      zs += __shfl_xor(zs, 4);
      zs += __shfl_xor(zs, 8);
      p0 = e0 / zs; p1 = e1 / zs; p2 = e2 / zs; p3 = e3 / zs;

      // local top-2 (ascending index => ties keep lower)
      v1 = p0; v2 = p1; i1 = 4 * tx; i2 = 4 * tx + 1;
      if (p1 > p0) { v1 = p1; i1 = 4 * tx + 1; v2 = p0; i2 = 4 * tx; }
      if (p2 > v1) { v2 = v1; i2 = i1; v1 = p2; i1 = 4 * tx + 2; }
      else if (p2 > v2) { v2 = p2; i2 = 4 * tx + 2; }
      if (p3 > v1) { v2 = v1; i2 = i1; v1 = p3; i1 = 4 * tx + 3; }
      else if (p3 > v2) { v2 = p3; i2 = 4 * tx + 3; }

      // butterfly merge across the 16 lanes of this token
#pragma unroll
      for (int s = 1; s <= 8; s <<= 1) {
        const float ov1 = __shfl_xor(v1, s); const int oi1 = __shfl_xor(i1, s);
        const float ov2 = __shfl_xor(v2, s); const int oi2 = __shfl_xor(i2, s);
        const bool o1 = (ov1 > v1) || (ov1 == v1 && oi1 < i1);
        if (o1) {
          const bool o2 = (ov2 > v1) || (ov2 == v1 && oi2 < i1);
          v2 = o2 ? ov2 : v1; i2 = o2 ? oi2 : i1;
          v1 = ov1; i1 = oi1;
        } else {
          const bool o2 = (ov1 > v2) || (ov1 == v2 && oi1 < i2);
          v2 = o2 ? ov1 : v2; i2 = o2 ? oi1 : i2;
        }
      }

      if (attempt == 1) break;
      // third-best prob (exclude i1, i2) for the set-boundary gap
      const int b4 = 4 * tx;
      float m3 = -1e30f;
      if (b4 + 0 != i1 && b4 + 0 != i2) m3 = fmaxf(m3, p0);
      if (b4 + 1 != i1 && b4 + 1 != i2) m3 = fmaxf(m3, p1);
      if (b4 + 2 != i1 && b4 + 2 != i2) m3 = fmaxf(m3, p2);
      if (b4 + 3 != i1 && b4 + 3 != i2) m3 = fmaxf(m3, p3);
      m3 = fmaxf(m3, __shfl_xor(m3, 1));
      m3 = fmaxf(m3, __shfl_xor(m3, 2));
      m3 = fmaxf(m3, __shfl_xor(m3, 4));
      m3 = fmaxf(m3, __shfl_xor(m3, 8));
      if ((v1 - v2 >= TAU) && (v2 - m3 >= TAU)) break;

      // near-tie: exact fp32 recompute (same ascending-FMA order as R1)
      const float* xr = Xg + (size_t)t * HD;
      const float* wr = Wg + (size_t)b4 * HD;
      float s0 = 0.f, s1 = 0.f, s2 = 0.f, s3 = 0.f;
      for (int h = 0; h < HD; h += 4) {
        const float4 xv = *(const float4*)(xr + h);
        const float4 a0 = *(const float4*)(wr + h);
        const float4 a1 = *(const float4*)(wr + HD + h);
        const float4 a2 = *(const float4*)(wr + 2 * HD + h);
        const float4 a3 = *(const float4*)(wr + 3 * HD + h);
        FMA4(s0, xv, a0) FMA4(s1, xv, a1) FMA4(s2, xv, a2) FMA4(s3, xv, a3)
      }
      l0 = s0; l1 = s1; l2 = s2; l3 = s3;
    }

    psum[0] += p0; psum[1] += p1; psum[2] += p2; psum[3] += p3;
    const float lz = m + logf(zs);
    if (tx == 0) {
      const float den = v1 + v2 + 1e-9f;
      out[2 * t]     = v1 / den;
      out[2 * t + 1] = v2 / den;
      out[2 * TT + 2 * t]     = (float)i1;
      out[2 * TT + 2 * t + 1] = (float)i2;
      atomicAdd(&cf[i1], 1.0f);
      atomicAdd(&cf[i2], 1.0f);
      zc += lz * lz;
    }
  }

#pragma unroll
  for (int j = 0; j < 4; ++j) {
    psum[j] += __shfl_xor(psum[j], 16);
    psum[j] += __shfl_xor(psum[j], 32);
  }
  if (lane < 16) {
#pragma unroll
    for (int j = 0; j < 4; ++j) psW[wv][4 * lane + j] = psum[j];
  }
  float z = zc;
#pragma unroll
  for (int s = 1; s <= 32; s <<= 1) z += __shfl_xor(z, s);
  if (lane == 0) zb[wv] = z;
  __syncthreads();

  if (tid < NE) {
    pP[blk * NE + tid] = psW[0][tid] + psW[1][tid] + psW[2][tid] + psW[3][tid];
    pC[blk * NE + tid] = cf[tid];
  }
  if (tid == 0) pZ[blk] = zb[0] + zb[1] + zb[2] + zb[3];
}

__global__ void router_final(const float* __restrict__ pP,
                             const float* __restrict__ pC,
                             const float* __restrict__ pZ,
                             float* __restrict__ out) {
  const int e = threadIdx.x;  // 64 threads = 1 wave
  float sP = 0.f, sC = 0.f;
  for (int b = 0; b < NBLK; ++b) {
    sP += pP[b * NE + e];
    sC += pC[b * NE + e];
  }
  const float f = sC * (1.0f / (TT * 2.0f));
  const float P = sP * (1.0f / (float)TT);
  out[4 * TT + 2 + e] = f;
  float term = f * P;
#pragma unroll
  for (int s = 1; s <= 32; s <<= 1) term += __shfl_xor(term, s);
  float zs = 0.f;
  for (int b = e; b < NBLK; b += NE) zs += pZ[b];
#pragma unroll
  for (int s = 1; s <= 32; s <<= 1) zs += __shfl_xor(zs, s);
  if (e == 0) {
    out[4 * TT]     = 0.01f * ((float)NE * term);
    out[4 * TT + 1] = 0.001f * (zs / (float)TT);
  }
}

// =====================================================================
// Fallback (validated round-1 fused kernel) for tiny ws_size.
// =====================================================================
__device__ __forceinline__ void async_copy16f(const float* src, float* dst) {
  async16((const void*)src, (void*)dst);
}

__launch_bounds__(256, 2)
__global__ void router_fused(const float* __restrict__ X,
                             const float* __restrict__ W,
                             float* __restrict__ out,
                             float* __restrict__ pP,
                             float* __restrict__ pC,
                             float* __restrict__ pZ) {
  __shared__ __align__(16) float sH[2][TM * 64];
  __shared__ __align__(16) float sW[2][NE * 64];
  __shared__ float psW[4][NE];
  __shared__ float cf[NE];
  __shared__ float zb[4];

  const int tid  = threadIdx.x;
  const int blk  = blockIdx.x;
  const int tx   = tid & 15;
  const int ty   = tid >> 4;
  const int wv   = tid >> 6;
  const int lane = tid & 63;

  if (tid < NE) cf[tid] = 0.0f;

  const int xoff = (tid & 15) << 4;
  const float* srcH[2];
  const float* srcW[4];
#pragma unroll
  for (int p = 0; p < 2; ++p) {
    const int r = ty + p * 16;
    const int sw = ((r >> 1) & 7) << 4;
    srcH[p] = X + (size_t)(blk * TM + r) * HD + ((xoff ^ sw) >> 2);
  }
#pragma unroll
  for (int p = 0; p < 4; ++p) {
    const int e = ty + p * 16;
    const int sw = ((e >> 2) & 7) << 4;
    srcW[p] = W + (size_t)e * HD + ((xoff ^ sw) >> 2);
  }

  auto stage = [&](int b, int kt) {
    const int o = kt * 64;
    float* dH = &sH[b][wv * 256];
    async_copy16f(srcH[0] + o, dH);
    async_copy16f(srcH[1] + o, dH + 1024);
    float* dW = &sW[b][wv * 256];
    async_copy16f(srcW[0] + o, dW);
    async_copy16f(srcW[1] + o, dW + 1024);
    async_copy16f(srcW[2] + o, dW + 2048);
    async_copy16f(srcW[3] + o, dW + 3072);
  };

  float acc[2][4] = {{0.f, 0.f, 0.f, 0.f}, {0.f, 0.f, 0.f, 0.f}};
  const int Hswz = (ty & 7) << 4;
  const int Wswz = (tx & 7) << 4;

  auto compute = [&](int b) {
    const char* hb = (const char*)(&sH[b][0]) + (ty << 9);
    const char* wb = (const char*)(&sW[b][0]) + (tx << 10);
#pragma unroll
    for (int h4 = 0; h4 < 16; ++h4) {
      const int oH = (h4 << 4) ^ Hswz;
      const int oW = (h4 << 4) ^ Wswz;
      const float4 h0 = *(const float4*)(hb + oH);
      const float4 h1 = *(const float4*)(hb + oH + 256);
      const float4 w0 = *(const float4*)(wb + oW);
      const float4 w1 = *(const float4*)(wb + oW + 256);
      const float4 w2 = *(const float4*)(wb + oW + 512);
      const float4 w3 = *(const float4*)(wb + oW + 768);
      FMA4(acc[0][0], h0, w0) FMA4(acc[0][1], h0, w1)
      FMA4(acc[0][2], h0, w2) FMA4(acc[0][3], h0, w3)
      FMA4(acc[1][0], h1, w0) FMA4(acc[1][1], h1, w1)
      FMA4(acc[1][2], h1, w2) FMA4(acc[1][3], h1, w3)
    }
  };

  int buf = 0;
  stage(0, 0);
  __syncthreads();
  for (int kt = 0; kt < 64; ++kt) {
    if (kt + 1 < 64) stage(buf ^ 1, kt + 1);
    compute(buf);
    __syncthreads();
    buf ^= 1;
  }

  float psum[4] = {0.f, 0.f, 0.f, 0.f};
  float zc = 0.0f;
#pragma unroll
  for (int i = 0; i < 2; ++i) {
    const float l0 = acc[i][0], l1 = acc[i][1], l2 = acc[i][2], l3 = acc[i][3];
    float m = fmaxf(fmaxf(l0, l1), fmaxf(l2, l3));
    m = fmaxf(m, __shfl_xor(m, 1));
    m = fmaxf(m, __shfl_xor(m, 2));
    m = fmaxf(m, __shfl_xor(m, 4));
    m = fmaxf(m, __shfl_xor(m, 8));
    const float e0 = expf(l0 - m), e1 = expf(l1 - m);
    const float e2 = expf(l2 - m), e3 = expf(l3 - m);
    float zs = (e0 + e1) + (e2 + e3);
    zs += __shfl_xor(zs, 1);
    zs += __shfl_xor(zs, 2);
    zs += __shfl_xor(zs, 4);
    zs += __shfl_xor(zs, 8);
    const float p0 = e0 / zs, p1 = e1 / zs, p2 = e2 / zs, p3 = e3 / zs;
    psum[0] += p0; psum[1] += p1; psum[2] += p2; psum[3] += p3;

    float v1 = p0, v2 = p1; int i1 = 4 * tx, i2 = 4 * tx + 1;
    if (p1 > p0) { v1 = p1; i1 = 4 * tx + 1; v2 = p0; i2 = 4 * tx; }
    if (p2 > v1) { v2 = v1; i2 = i1; v1 = p2; i1 = 4 * tx + 2; }
    else if (p2 > v2) { v2 = p2; i2 = 4 * tx + 2; }
    if (p3 > v1) { v2 = v1; i2 = i1; v1 = p3; i1 = 4 * tx + 3; }
    else if (p3 > v2) { v2 = p3; i2 = 4 * tx + 3; }

#pragma unroll
    for (int s = 1; s <= 8; s <<= 1) {
      const float ov1 = __shfl_xor(v1, s); const int oi1 = __shfl_xor(i1, s);
      const float ov2 = __shfl_xor(v2, s); const int oi2 = __shfl_xor(i2, s);
      const bool o1 = (ov1 > v1) || (ov1 == v1 && oi1 < i1);
      if (o1) {
        const bool o2 = (ov2 > v1) || (ov2 == v1 && oi2 < i1);
        v2 = o2 ? ov2 : v1; i2 = o2 ? oi2 : i1;
        v1 = ov1; i1 = oi1;
      } else {
        const bool o2 = (ov1 > v2) || (ov1 == v2 && oi1 < i2);
        v2 = o2 ? ov1 : v2; i2 = o2 ? oi1 : i2;
      }
    }

    const float lz = m + logf(zs);
    if (tx == 0) {
      const int t = blk * TM + 2 * ty + i;
      const float den = v1 + v2 + 1e-9f;
      out[2 * t]     = v1 / den;
      out[2 * t + 1] = v2 / den;
      out[2 * TT + 2 * t]     = (float)i1;
      out[2 * TT + 2 * t + 1] = (float)i2;
      atomicAdd(&cf[i1], 1.0f);
      atomicAdd(&cf[i2], 1.0f);
      zc += lz * lz;
    }
  }

#pragma unroll
  for (int j = 0; j < 4; ++j) {
    psum[j] += __shfl_xor(psum[j], 16);
    psum[j] += __shfl_xor(psum[j], 32);
  }
  if (lane < 16) {
#pragma unroll
    for (int j = 0; j < 4; ++j) psW[wv][4 * lane + j] = psum[j];
  }
  float z = zc;
#pragma unroll
  for (int s = 1; s <= 32; s <<= 1) z += __shfl_xor(z, s);
  if (lane == 0) zb[wv] = z;
  __syncthreads();

  if (tid < NE) {
    pP[blk * NE + tid] = psW[0][tid] + psW[1][tid] + psW[2][tid] + psW[3][tid];
    pC[blk * NE + tid] = cf[tid];
  }
  if (tid == 0) pZ[blk] = zb[0] + zb[1] + zb[2] + zb[3];
}

extern "C" void kernel_launch(void* const* d_in, const int* in_sizes, int n_in,
                              void* d_out, int out_size, void* d_ws, size_t ws_size,
                              hipStream_t stream) {
  const float* X = (const float*)d_in[0];   // [16384, 4096] f32
  const float* W = (const float*)d_in[1];   // [64, 4096] f32
  float* out = (float*)d_out;
  (void)in_sizes; (void)n_in; (void)out_size;

  // ws layout: WH (ushort 64*4096), WL (ushort), part (f32 TT*NE), pP, pC, pZ
  const size_t WHALF = (size_t)NE * HD;                 // ushorts per plane
  const size_t PARTF = (size_t)TT * NE;                 // floats
  const size_t AUXF  = (size_t)NBLK * NE * 2 + NBLK;
  const size_t NEEDB = WHALF * 2 * sizeof(unsigned short) +
                       (PARTF + AUXF) * sizeof(float);

  if (ws_size >= NEEDB) {
    unsigned short* WH = (unsigned short*)d_ws;
    unsigned short* WL = WH + WHALF;
    float* part = (float*)(WL + WHALF);
    float* pP = part + PARTF;
    float* pC = pP + NBLK * NE;
    float* pZ = pC + NBLK * NE;
    wconv<<<dim3(256), dim3(256), 0, stream>>>(W, WH, WL);
    gemm_mfma<<<dim3(NB5), dim3(256), 0, stream>>>(X, WH, WL, part);
    router_epilogue<<<dim3(NBLK), dim3(256), 0, stream>>>(part, X, W, out, pP, pC, pZ);
    router_final<<<dim3(1), dim3(NE), 0, stream>>>(pP, pC, pZ, out);
  } else {
    float* pP = (float*)d_ws;
    float* pC = pP + NBLK * NE;
    float* pZ = pC + NBLK * NE;
    router_fused<<<dim3(NBLK), dim3(256), 0, stream>>>(X, W, out, pP, pC, pZ);
    router_final<<<dim3(1), dim3(NE), 0, stream>>>(pP, pC, pZ, out);
  }
}